// Round 1
// 520.157 us; speedup vs baseline: 1.2170x; 1.2170x over previous
//
#include <hip/hip_runtime.h>

#define N_ 32
#define C_ 128
#define H_ 32
#define W_ 32
#define T_ 12
#define R_ 64
#define HW_ (H_*W_)           // 1024
#define HWT_ (HW_*T_)         // 12288
#define CHWT_ ((size_t)C_*HW_*T_)  // 1572864
#define NCHUNK_ 16            // hw chunks of 64 for stats

__device__ __forceinline__ float sigm(float v) {
    return 1.0f / (1.0f + __expf(-v));
}

// K1: fused stats — ONE pass over x producing both
//   ts_in[n,t,hw]  = mean_c x[n,c,hw,t]          (channel mean)
//   pooled partials: pooled_p[chunk,n,t,c] = sum_{hw in chunk} x[n,c,hw,t]
// block = (hw-chunk of 64, n), 256 threads = 4 waves.
// lane owns hw = chunk*64+lane, reads its 12 t as 3 aligned float4 (dense).
// waves stride over c (wave w: c = w, w+4, ...).
__global__ __launch_bounds__(256) void k_stats(const float* __restrict__ x,
                                               float* __restrict__ ts_in,
                                               float* __restrict__ pooled_p) {
    int chunk = blockIdx.x;      // 0..15
    int n = blockIdx.y;
    int tid = threadIdx.x;
    int wave = tid >> 6;
    int lane = tid & 63;
    int hw = chunk * 64 + lane;

    __shared__ float pooled_l[T_ * C_];     // [t][c], 6 KB — each c owned by one wave
    __shared__ float ts_l[4][64 * T_];      // per-wave ts partials, 12 KB

    const float* xb = x + (size_t)n * CHWT_ + (size_t)hw * T_;

    float ts_acc[T_];
    #pragma unroll
    for (int j = 0; j < T_; ++j) ts_acc[j] = 0.f;

    #pragma unroll 2
    for (int ci = 0; ci < C_ / 4; ++ci) {
        int c = wave + 4 * ci;
        const float4* p = (const float4*)(xb + (size_t)c * HWT_);
        float4 v0 = p[0], v1 = p[1], v2 = p[2];
        float v[T_] = {v0.x, v0.y, v0.z, v0.w,
                       v1.x, v1.y, v1.z, v1.w,
                       v2.x, v2.y, v2.z, v2.w};
        #pragma unroll
        for (int j = 0; j < T_; ++j) ts_acc[j] += v[j];
        // butterfly-reduce over the 64 hw of this chunk (all in this wave)
        #pragma unroll
        for (int d = 1; d < 64; d <<= 1) {
            #pragma unroll
            for (int j = 0; j < T_; ++j) v[j] += __shfl_xor(v[j], d, 64);
        }
        // lane t writes pooled sum for (t, c); static-index select (no scratch)
        if (lane < T_) {
            float o = v[0];
            #pragma unroll
            for (int j = 1; j < T_; ++j) if (lane == j) o = v[j];
            pooled_l[lane * C_ + c] = o;
        }
    }

    #pragma unroll
    for (int j = 0; j < T_; ++j) ts_l[wave][lane * T_ + j] = ts_acc[j];
    __syncthreads();

    // ts_in: reduce 4 wave-partials, scale by 1/128
    for (int i = tid; i < 64 * T_; i += 256) {
        float s = ts_l[0][i] + ts_l[1][i] + ts_l[2][i] + ts_l[3][i];
        int hwl = i / T_;
        int t = i - hwl * T_;
        ts_in[(n * T_ + t) * HW_ + chunk * 64 + hwl] = s * (1.0f / 128.0f);
    }
    // pooled partial out (coalesced); k_lin sums the 16 chunks
    for (int i = tid; i < T_ * C_; i += 256)
        pooled_p[((size_t)chunk * N_ + n) * (T_ * C_) + i] = pooled_l[i];
}

// K2: TS[n,r,s] = sigmoid(conv3x3(ts_in)[n,r,h,w] + ts_b[r])
__global__ __launch_bounds__(256) void k_conv(const float* __restrict__ ts_in,
                                              const float* __restrict__ ts_w,
                                              const float* __restrict__ ts_b,
                                              float* __restrict__ TS) {
    int h = blockIdx.x;
    int n = blockIdx.y;
    int tid = threadIdx.x;
    __shared__ float rows[3 * T_ * 34];   // 1224 floats
    __shared__ float wl[R_ * 108];        // 6912 floats
    for (int i = tid; i < 3 * T_ * 34; i += 256) {
        int kh = i / (T_ * 34);
        int rem = i - kh * (T_ * 34);
        int t = rem / 34;
        int wp = rem - t * 34;
        int hr = h + kh - 1;
        float v = 0.f;
        if (wp >= 1 && wp <= 32 && hr >= 0 && hr < H_)
            v = ts_in[((n * T_ + t) * H_ + hr) * W_ + (wp - 1)];
        rows[i] = v;
    }
    for (int i = tid; i < R_ * 108; i += 256) wl[i] = ts_w[i];
    __syncthreads();
    int r = tid >> 2;
    int j = tid & 3;
    float acc[8];
    float b = ts_b[r];
    #pragma unroll
    for (int wi = 0; wi < 8; ++wi) acc[wi] = b;
    for (int t = 0; t < T_; ++t) {
        #pragma unroll
        for (int kh = 0; kh < 3; ++kh) {
            #pragma unroll
            for (int kw = 0; kw < 3; ++kw) {
                float wt = wl[r * 108 + t * 9 + kh * 3 + kw];
                const float* rp = &rows[(kh * T_ + t) * 34 + kw];
                #pragma unroll
                for (int wi = 0; wi < 8; ++wi) {
                    acc[wi] += rp[j + 4 * wi] * wt;
                }
            }
        }
    }
    float* outp = TS + (size_t)(n * R_ + r) * HW_ + h * W_;
    #pragma unroll
    for (int wi = 0; wi < 8; ++wi) {
        outp[j + 4 * wi] = sigm(acc[wi]);
    }
}

// K3: TC[n,t,r] and SC[n,c,r]; block per n. Sums the 16 pooled partials.
__global__ __launch_bounds__(256) void k_lin(const float* __restrict__ pooled_p,
                                             const float* __restrict__ tc_w,
                                             const float* __restrict__ tc_b,
                                             const float* __restrict__ sc_w,
                                             const float* __restrict__ sc_b,
                                             float* __restrict__ TC,
                                             float* __restrict__ SC) {
    int n = blockIdx.x;
    int tid = threadIdx.x;
    __shared__ float pl[T_ * C_];    // 1536
    __shared__ float twt[C_ * R_];   // 8192, [c][r]
    __shared__ float sw[R_ * T_];    // 768
    for (int i = tid; i < T_ * C_; i += 256) {
        float s = 0.f;
        #pragma unroll
        for (int k = 0; k < NCHUNK_; ++k)
            s += pooled_p[((size_t)k * N_ + n) * (T_ * C_) + i];
        pl[i] = s * (1.0f / 1024.0f);
    }
    for (int i = tid; i < C_ * R_; i += 256) {
        int r = i >> 7;
        int c = i & 127;
        twt[c * R_ + r] = tc_w[i];
    }
    for (int i = tid; i < R_ * T_; i += 256) sw[i] = sc_w[i];
    __syncthreads();
    for (int o = tid; o < T_ * R_; o += 256) {
        int t = o >> 6;
        int r = o & 63;
        float acc = tc_b[r];
        #pragma unroll 4
        for (int c = 0; c < C_; ++c) acc += pl[t * C_ + c] * twt[c * R_ + r];
        TC[n * T_ * R_ + o] = sigm(acc);
    }
    for (int o = tid; o < C_ * R_; o += 256) {
        int c = o >> 6;
        int r = o & 63;
        float acc = sc_b[r];
        #pragma unroll
        for (int t = 0; t < T_; ++t) acc += pl[t * C_ + c] * sw[r * T_ + t];
        SC[n * C_ * R_ + o] = sigm(acc);
    }
}

// K4: out[n,c,hw,t] = relu( (Σ_r TS[n,r,s]·TC[n,t,r]·SC[n,c,r]) * x[n,c,hw,t] )
// SC rows are block-uniform per c -> read via uniform float4 loads (scalar path,
// s_load + SGPR operand in v_fma). No per-c LDS. 4 accumulator chains. x loads
// grouped 4-wide for VMEM ILP.
__global__ __launch_bounds__(192) void k_main(const float* __restrict__ x,
                                              const float* __restrict__ TS,
                                              const float* __restrict__ TC,
                                              const float* __restrict__ SC,
                                              float* __restrict__ out) {
    int schunk = blockIdx.x;   // 0..63
    int n = blockIdx.y;
    int tid = threadIdx.x;
    __shared__ float tst[R_ * 16];                // 4 KB
    __shared__ float tcl[T_ * R_];                // 3 KB
    int s0 = schunk * 16;
    for (int i = tid; i < R_ * 16; i += 192) {
        int r = i >> 4;
        int sl = i & 15;
        tst[i] = TS[(size_t)(n * R_ + r) * HW_ + s0 + sl];
    }
    for (int i = tid; i < T_ * R_; i += 192) tcl[i] = TC[n * T_ * R_ + i];
    __syncthreads();
    int sl = tid / T_;
    int t = tid - sl * T_;
    float w[R_];
    #pragma unroll
    for (int r = 0; r < R_; ++r) w[r] = tcl[t * R_ + r] * tst[r * 16 + sl];
    size_t base = (size_t)n * CHWT_ + (size_t)s0 * T_ + tid;
    const float* scb = SC + (size_t)n * C_ * R_;

    for (int cg = 0; cg < C_; cg += 4) {
        float xg[4];
        #pragma unroll
        for (int cc = 0; cc < 4; ++cc)
            xg[cc] = x[base + (size_t)(cg + cc) * HWT_];
        #pragma unroll
        for (int cc = 0; cc < 4; ++cc) {
            const float4* sp = (const float4*)(scb + (size_t)(cg + cc) * R_);
            float a0 = 0.f, a1 = 0.f, a2 = 0.f, a3 = 0.f;
            #pragma unroll
            for (int r4 = 0; r4 < R_ / 4; ++r4) {
                float4 q = sp[r4];
                a0 = fmaf(q.x, w[4 * r4 + 0], a0);
                a1 = fmaf(q.y, w[4 * r4 + 1], a1);
                a2 = fmaf(q.z, w[4 * r4 + 2], a2);
                a3 = fmaf(q.w, w[4 * r4 + 3], a3);
            }
            float acc = (a0 + a1) + (a2 + a3);
            float rr = acc * xg[cc];
            size_t idx = base + (size_t)(cg + cc) * HWT_;
            out[idx] = rr > 0.f ? rr : 0.f;
        }
    }
}

extern "C" void kernel_launch(void* const* d_in, const int* in_sizes, int n_in,
                              void* d_out, int out_size, void* d_ws, size_t ws_size,
                              hipStream_t stream) {
    const float* x    = (const float*)d_in[0];
    const float* ts_w = (const float*)d_in[1];
    const float* ts_b = (const float*)d_in[2];
    const float* tc_w = (const float*)d_in[3];
    const float* tc_b = (const float*)d_in[4];
    const float* sc_w = (const float*)d_in[5];
    const float* sc_b = (const float*)d_in[6];
    float* out = (float*)d_out;

    float* ws       = (float*)d_ws;
    float* ts_in    = ws;                          // 393216 floats
    float* pooled_p = ts_in + 393216;              // 16*32*12*128 = 786432
    float* TS       = pooled_p + 786432;           // 2097152
    float* TC       = TS + 2097152;                // 24576
    float* SC       = TC + 24576;                  // 262144   (total ~14.3 MB)

    hipLaunchKernelGGL(k_stats, dim3(NCHUNK_, 32), dim3(256), 0, stream, x, ts_in, pooled_p);
    hipLaunchKernelGGL(k_conv, dim3(32, 32), dim3(256), 0, stream, ts_in, ts_w, ts_b, TS);
    hipLaunchKernelGGL(k_lin, dim3(32), dim3(256), 0, stream,
                       pooled_p, tc_w, tc_b, sc_w, sc_b, TC, SC);
    hipLaunchKernelGGL(k_main, dim3(64, 32), dim3(192), 0, stream, x, TS, TC, SC, out);
}